// Round 15
// baseline (1161.005 us; speedup 1.0000x reference)
//
#include <hip/hip_runtime.h>
#include <hip/hip_fp16.h>

#define N_NODES 10000
#define NPAD    10016   // multiple of 16
#define N_EDGES 60000
#define EPAD    60032

typedef _Float16 f16;
typedef f16 f16x8 __attribute__((ext_vector_type(8)));
typedef f16 f16x2 __attribute__((ext_vector_type(2)));
typedef float f32x4 __attribute__((ext_vector_type(4)));

#define SV2(v, j) __builtin_shufflevector(v, v, 2 * (j), 2 * (j) + 1)

#if __has_builtin(__builtin_amdgcn_fdot2)
__device__ __forceinline__ float FDOT2(f16x2 a, f16x2 b, float c) {
    return __builtin_amdgcn_fdot2(a, b, c, false);
}
#else
__device__ __forceinline__ float FDOT2(f16x2 a, f16x2 b, float c) {
    return c + (float)a[0] * (float)b[0] + (float)a[1] * (float)b[1];
}
#endif

// ---- node encoder: h = relu(x@nW1+nb1)@nW2+nb2, + f16 copy, + hb -----------
__global__ void k_node_enc(const float* __restrict__ x, const float* __restrict__ W1,
                           const float* __restrict__ b1, const float* __restrict__ W2,
                           const float* __restrict__ b2, const float* __restrict__ kb3,
                           float* __restrict__ h, f16* __restrict__ h16,
                           float* __restrict__ hb) {
    __shared__ float t[4][64];
    __shared__ float t2[4][64];
    int g = threadIdx.x >> 6, j = threadIdx.x & 63;
    int node = blockIdx.x * 4 + g;
    float acc = b1[j];
#pragma unroll
    for (int i = 0; i < 6; ++i) acc += x[node * 6 + i] * W1[i * 64 + j];
    t[g][j] = fmaxf(acc, 0.f);
    __syncthreads();
    float acc2 = b2[j];
#pragma unroll
    for (int i = 0; i < 64; ++i) acc2 += t[g][i] * W2[i * 64 + j];
    h[node * 64 + j] = acc2;
    h16[node * 64 + j] = (f16)acc2;
    t2[g][j] = acc2;
    __syncthreads();
    float hbv = 0.f;
#pragma unroll
    for (int i = 0; i < 64; ++i) hbv += t2[g][i] * kb3[i * 64 + j];
    hb[node * 64 + j] = hbv;
}

// ---------------- condition encoder -----------------------------------------
__global__ void k_cond_enc(const float* __restrict__ cond, const float* __restrict__ scl,
                           const float* __restrict__ W1, const float* __restrict__ b1,
                           const float* __restrict__ W2, const float* __restrict__ b2,
                           float* __restrict__ u, float* __restrict__ out_u) {
    __shared__ float t[4][64];
    __shared__ float cat[4][14];
    int g = threadIdx.x >> 6, j = threadIdx.x & 63;
    if (threadIdx.x < 56) {
        int b = threadIdx.x / 14, i = threadIdx.x % 14;
        cat[b][i] = (i < 10) ? cond[b * 10 + i] : scl[b * 4 + (i - 10)];
    }
    __syncthreads();
    float acc = b1[j];
#pragma unroll
    for (int i = 0; i < 14; ++i) acc += cat[g][i] * W1[i * 64 + j];
    t[g][j] = fmaxf(acc, 0.f);
    __syncthreads();
    float acc2 = b2[j];
#pragma unroll
    for (int i = 0; i < 64; ++i) acc2 += t[g][i] * W2[i * 64 + j];
    u[g * 64 + j] = acc2;
    out_u[g * 64 + j] = acc2;
}

// ---------------- degree (dst) + csr count (src), one pass -------------------
__global__ void k_degcnt(const int* __restrict__ ei, float* __restrict__ deg,
                         int* __restrict__ cnt) {
    int e = blockIdx.x * 256 + threadIdx.x;
    if (e < N_EDGES) {
        atomicAdd(&deg[ei[N_EDGES + e]], 1.0f);
        atomicAdd(&cnt[ei[e]], 1);
    }
}
__global__ void k_deg_inv(float* __restrict__ deg) {
    int n = blockIdx.x * 256 + threadIdx.x;
    if (n < N_NODES) deg[n] = 1.0f / fmaxf(deg[n], 1.0f);
}

// ---------------- src-CSR scan + fill ----------------------------------------
__global__ void k_csr_scan(const int* __restrict__ cnt, int* __restrict__ srcPtr,
                           int* __restrict__ cursor) {
    __shared__ int part[256];
    int t = threadIdx.x;
    int base = t * 40;
    int s = 0;
#pragma unroll 1
    for (int i = 0; i < 40; ++i) { int idx = base + i; if (idx < NPAD) s += cnt[idx]; }
    part[t] = s;
    __syncthreads();
    if (t == 0) {
        int run = 0;
        for (int i = 0; i < 256; ++i) { int v = part[i]; part[i] = run; run += v; }
    }
    __syncthreads();
    int run = part[t];
#pragma unroll 1
    for (int i = 0; i < 40; ++i) {
        int idx = base + i;
        if (idx <= NPAD) {
            srcPtr[idx] = run; cursor[idx] = run;
            if (idx < NPAD) run += cnt[idx];
        }
    }
}
__global__ void k_csr_fill(const int* __restrict__ src, int* __restrict__ cursor,
                           int* __restrict__ srcIdx) {
    int e = blockIdx.x * 256 + threadIdx.x;
    if (e < N_EDGES) { int p = atomicAdd(&cursor[src[e]], 1); srcIdx[p] = e; }
}

// ------- permute kW3 -> Mp2[c][i] = kW3[k][i*64+o], c = o*256+k, f16 ---------
__global__ void k_mp2(const float* __restrict__ kW3, f16* __restrict__ Mp2) {
    int k = threadIdx.x, o = blockIdx.x, ib = blockIdx.y;
#pragma unroll
    for (int j = 0; j < 8; ++j) {
        int i = ib * 8 + j;
        Mp2[((size_t)o * 256 + k) * 64 + i] = (f16)kW3[(size_t)k * 4096 + i * 64 + o];
    }
}

// ---------------- fused edge MLP (k1 in LDS, k2 fp16 out) --------------------
__global__ __launch_bounds__(256) void k_edge12(const float* __restrict__ ea, const int* __restrict__ ei,
                                                const int* __restrict__ batch, const float* __restrict__ u,
                                                const float* __restrict__ W1, const float* __restrict__ b1,
                                                const float* __restrict__ W2, const float* __restrict__ b2,
                                                f16* __restrict__ k2) {
    __shared__ float u_s[256];
    __shared__ float ea_s[16][6];
    __shared__ int b_s[16];
    __shared__ float k1_s[16][128];
    int tid = threadIdx.x;
    int e0 = blockIdx.x * 16;
    u_s[tid] = u[tid];
    if (tid < 96) {
        int e = tid / 6, i = tid % 6;
        int eg = e0 + e;
        ea_s[e][i] = (eg < N_EDGES) ? ea[(size_t)eg * 6 + i] : 0.f;
    }
    if (tid < 16) {
        int eg = e0 + tid;
        b_s[tid] = (eg < N_EDGES) ? batch[ei[eg]] : 0;
    }
    __syncthreads();
    int j = tid & 127;
#pragma unroll 1
    for (int p = 0; p < 8; ++p) {
        int e = p * 2 + (tid >> 7);
        float acc = b1[j];
#pragma unroll
        for (int i = 0; i < 6; ++i) acc += ea_s[e][i] * W1[i * 128 + j];
        const float* ur = u_s + b_s[e] * 64;
#pragma unroll
        for (int i = 0; i < 64; ++i) acc += ur[i] * W1[(6 + i) * 128 + j];
        k1_s[e][j] = fmaxf(acc, 0.f);
    }
    __syncthreads();
    float acc2[16];
#pragma unroll
    for (int e = 0; e < 16; ++e) acc2[e] = b2[tid];
    for (int i = 0; i < 128; ++i) {
        float w = W2[(size_t)i * 256 + tid];
#pragma unroll
        for (int e = 0; e < 16; ++e) acc2[e] += k1_s[e][i] * w;
    }
#pragma unroll
    for (int e = 0; e < 16; ++e) {
        int eg = e0 + e;
        k2[(size_t)eg * 256 + tid] = (f16)((eg < N_EDGES) ? fmaxf(acc2[e], 0.f) : 0.f);
    }
}

// ---- G-tile + message + scatter-mean ----------------------------------------
// grid (8, NPAD/16): og = blockIdx.x (fastest -> og pinned per XCD, k2 rows
// shared across XCDs via L3 in the same time window), node-group = blockIdx.y.
// Phase 1 (unchanged from r14): G[n][o][k] via MFMA into 64 KB LDS (swizzled).
// Phase 2: 2 threads per edge, each computes 4 o's; k2 8-chunk register batch;
// 4 independent fdot2 chains; 16 B-contiguous atomic quad.
__global__ __launch_bounds__(256) void k_gmsg(const f16* __restrict__ k2, const f16* __restrict__ Mp2,
                                              const f16* __restrict__ h16, const float* __restrict__ hb,
                                              const int* __restrict__ ei, const int* __restrict__ srcPtr,
                                              const int* __restrict__ srcIdx, const float* __restrict__ dinv,
                                              float* __restrict__ agg) {
    __shared__ __align__(16) f16 G[16 * 8 * 256];   // 64 KB
    char* Gb = (char*)G;
    int tid = threadIdx.x, wave = tid >> 6, lane = tid & 63;
    int og = blockIdx.x;
    int n0 = blockIdx.y * 16;
    // ---- phase 1: each wave owns 512 c-cols (= 2 o values), 16 node rows ----
    f16x8 a0 = *(const f16x8*)(h16 + (size_t)(n0 + (lane & 15)) * 64 + (lane >> 4) * 8);
    f16x8 a1 = *(const f16x8*)(h16 + (size_t)(n0 + (lane & 15)) * 64 + 32 + (lane >> 4) * 8);
    const f16* Brow = Mp2 + ((size_t)og * 2048 + wave * 512 + (lane & 15)) * 64 + (lane >> 4) * 8;
    f16x8 p0a = *(const f16x8*)(Brow);
    f16x8 p0b = *(const f16x8*)(Brow + 32);
    f16x8 p1a = *(const f16x8*)(Brow + 1024);
    f16x8 p1b = *(const f16x8*)(Brow + 1024 + 32);
#pragma unroll 1
    for (int nf = 0; nf < 32; ++nf) {
        f16x8 c0 = p0a, c1 = p0b;
        p0a = p1a; p0b = p1b;
        if (nf < 30) {
            p1a = *(const f16x8*)(Brow + (nf + 2) * 1024);
            p1b = *(const f16x8*)(Brow + (nf + 2) * 1024 + 32);
        }
        f32x4 acc = {};
        acc = __builtin_amdgcn_mfma_f32_16x16x32_f16(a0, c0, acc, 0, 0, 0);
        acc = __builtin_amdgcn_mfma_f32_16x16x32_f16(a1, c1, acc, 0, 0, 0);
        int olocal = wave * 2 + (nf >> 4);
        int kk = ((nf & 15) << 4) + (lane & 15);
        int gq = kk >> 3, grb = (kk & 7) * 2;
#pragma unroll
        for (int jj = 0; jj < 4; ++jj) {
            int ro = ((lane >> 4) * 4 + jj) * 8 + olocal;
            *(f16*)(Gb + ro * 512 + ((gq ^ (ro & 31)) << 4) + grb) = (f16)acc[jj];
        }
    }
    __syncthreads();
    // ---- phase 2: edges with src in [n0, n0+16); 2 threads/edge x 4 o -------
    int sp0 = srcPtr[n0];
    int cnt2 = (srcPtr[n0 + 16] - sp0) << 1;
#pragma unroll 1
    for (int p = tid; p < cnt2; p += 256) {
        int e = srcIdx[sp0 + (p >> 1)];
        int oq = p & 1;                      // which o-quad
        int sn = ei[e];
        int d = ei[N_EDGES + e];
        int rb = (sn - n0) * 8 + oq * 4;
        const char* g0 = Gb + (size_t)(rb + 0) * 512; int s0 = (rb + 0) & 31;
        const char* g1 = Gb + (size_t)(rb + 1) * 512; int s1 = (rb + 1) & 31;
        const char* g2 = Gb + (size_t)(rb + 2) * 512; int s2 = (rb + 2) & 31;
        const char* g3 = Gb + (size_t)(rb + 3) * 512; int s3 = (rb + 3) & 31;
        const f16* kp = k2 + (size_t)e * 256;
        float m0 = 0.f, m1 = 0.f, m2 = 0.f, m3 = 0.f;
#pragma unroll
        for (int kb = 0; kb < 32; kb += 8) {
            f16x8 kv[8];
#pragma unroll
            for (int c = 0; c < 8; ++c) kv[c] = *(const f16x8*)(kp + (kb + c) * 8);
#pragma unroll
            for (int c = 0; c < 8; ++c) {
                int kc = kb + c;
                f16x8 gv0 = *(const f16x8*)(g0 + ((kc ^ s0) << 4));
                m0 = FDOT2(SV2(kv[c], 0), SV2(gv0, 0), m0);
                m0 = FDOT2(SV2(kv[c], 1), SV2(gv0, 1), m0);
                m0 = FDOT2(SV2(kv[c], 2), SV2(gv0, 2), m0);
                m0 = FDOT2(SV2(kv[c], 3), SV2(gv0, 3), m0);
                f16x8 gv1 = *(const f16x8*)(g1 + ((kc ^ s1) << 4));
                m1 = FDOT2(SV2(kv[c], 0), SV2(gv1, 0), m1);
                m1 = FDOT2(SV2(kv[c], 1), SV2(gv1, 1), m1);
                m1 = FDOT2(SV2(kv[c], 2), SV2(gv1, 2), m1);
                m1 = FDOT2(SV2(kv[c], 3), SV2(gv1, 3), m1);
                f16x8 gv2 = *(const f16x8*)(g2 + ((kc ^ s2) << 4));
                m2 = FDOT2(SV2(kv[c], 0), SV2(gv2, 0), m2);
                m2 = FDOT2(SV2(kv[c], 1), SV2(gv2, 1), m2);
                m2 = FDOT2(SV2(kv[c], 2), SV2(gv2, 2), m2);
                m2 = FDOT2(SV2(kv[c], 3), SV2(gv2, 3), m2);
                f16x8 gv3 = *(const f16x8*)(g3 + ((kc ^ s3) << 4));
                m3 = FDOT2(SV2(kv[c], 0), SV2(gv3, 0), m3);
                m3 = FDOT2(SV2(kv[c], 1), SV2(gv3, 1), m3);
                m3 = FDOT2(SV2(kv[c], 2), SV2(gv3, 2), m3);
                m3 = FDOT2(SV2(kv[c], 3), SV2(gv3, 3), m3);
            }
        }
        int ogo = (og << 3) + (oq << 2);
        float dv = dinv[d];
        const float* hp = hb + (size_t)sn * 64 + ogo;
        float* ap = agg + (size_t)d * 64 + ogo;
        atomicAdd(ap + 0, (m0 + hp[0]) * dv);
        atomicAdd(ap + 1, (m1 + hp[1]) * dv);
        atomicAdd(ap + 2, (m2 + hp[2]) * dv);
        atomicAdd(ap + 3, (m3 + hp[3]) * dv);
    }
}

// ---- node update: h' = relu(agg + h@root + bias); also emits f16 copy,
// ---- next-layer hb, and re-zeroes agg for the next k_gmsg ------------------
__global__ void k_update(float* __restrict__ agg, const float* __restrict__ h,
                         const float* __restrict__ root, const float* __restrict__ bias,
                         const float* __restrict__ kb3, float* __restrict__ hn,
                         f16* __restrict__ hn16, float* __restrict__ hb) {
    __shared__ float t[4][64];
    int g = threadIdx.x >> 6, j = threadIdx.x & 63;
    int node = blockIdx.x * 4 + g;
    t[g][j] = h[node * 64 + j];
    __syncthreads();
    float acc = agg[node * 64 + j] + bias[j];
    agg[node * 64 + j] = 0.f;
#pragma unroll
    for (int i = 0; i < 64; ++i) acc += t[g][i] * root[i * 64 + j];
    float v = fmaxf(acc, 0.f);
    hn[node * 64 + j] = v;
    hn16[node * 64 + j] = (f16)v;
    __syncthreads();
    t[g][j] = v;
    __syncthreads();
    float hbv = 0.f;
#pragma unroll
    for (int i = 0; i < 64; ++i) hbv += t[g][i] * kb3[i * 64 + j];
    hb[node * 64 + j] = hbv;
}

// ---------------- output head ------------------------------------------------
__global__ void k_out(const float* __restrict__ h, const float* __restrict__ oW,
                      const float* __restrict__ ob, float* __restrict__ out) {
    int wg = (blockIdx.x * 256 + threadIdx.x) >> 6;
    int lane = threadIdx.x & 63;
    if (wg >= N_NODES) return;
    float p = h[wg * 64 + lane] * oW[lane];
#pragma unroll
    for (int s = 32; s > 0; s >>= 1) p += __shfl_xor(p, s);
    if (lane == 0) out[wg] = p + ob[0];
}

__global__ void k_sentinel(float* out) { out[0] = 1e30f; }

extern "C" void kernel_launch(void* const* d_in, const int* in_sizes, int n_in,
                              void* d_out, int out_size, void* d_ws, size_t ws_size,
                              hipStream_t stream) {
    const float* x          = (const float*)d_in[0];
    const float* edge_attr  = (const float*)d_in[1];
    const float* conditions = (const float*)d_in[2];
    const float* scale      = (const float*)d_in[3];
    const int*   edge_index = (const int*)d_in[4];
    const int*   batch      = (const int*)d_in[5];
    const float* nW1 = (const float*)d_in[6];  const float* nb1 = (const float*)d_in[7];
    const float* nW2 = (const float*)d_in[8];  const float* nb2 = (const float*)d_in[9];
    const float* cW1 = (const float*)d_in[10]; const float* cb1 = (const float*)d_in[11];
    const float* cW2 = (const float*)d_in[12]; const float* cb2 = (const float*)d_in[13];
    const float* kW1 = (const float*)d_in[14]; const float* kb1 = (const float*)d_in[15];
    const float* kW2 = (const float*)d_in[16]; const float* kb2 = (const float*)d_in[17];
    const float* kW3 = (const float*)d_in[18]; const float* kb3 = (const float*)d_in[19];
    const float* root = (const float*)d_in[20]; const float* conv_bias = (const float*)d_in[21];
    const float* oW  = (const float*)d_in[22]; const float* ob  = (const float*)d_in[23];
    float* out = (float*)d_out;

    char* ws = (char*)d_ws;
    size_t off = 0;
    auto alloc = [&](size_t bytes) -> char* {
        char* p = ws + off;
        off += (bytes + 255) & ~(size_t)255;
        return p;
    };
    float* h_a    = (float*)alloc((size_t)N_NODES * 64 * 4);
    float* h_b    = (float*)alloc((size_t)N_NODES * 64 * 4);
    f16*   h16_a  = (f16*)alloc((size_t)NPAD * 64 * 2);
    f16*   h16_b  = (f16*)alloc((size_t)NPAD * 64 * 2);
    float* agg    = (float*)alloc((size_t)N_NODES * 64 * 4);
    float* hb     = (float*)alloc((size_t)N_NODES * 64 * 4);
    float* u      = (float*)alloc(256 * 4);
    float* degcnt = (float*)alloc((size_t)2 * NPAD * 4);   // deg | cnt (one memset)
    float* deg    = degcnt;
    int*   cnt    = (int*)(degcnt + NPAD);
    int*   srcPtr = (int*)alloc((size_t)(NPAD + 1) * 4);
    int*   cursor = (int*)alloc((size_t)(NPAD + 1) * 4);
    int*   srcIdx = (int*)alloc((size_t)N_EDGES * 4);
    f16*   k2     = (f16*)alloc((size_t)EPAD * 256 * 2);
    f16*   Mp2    = (f16*)alloc((size_t)16384 * 64 * 2);
    // total ~48 MB

    if (off > ws_size) {  // workspace too small: distinct sentinel
        k_sentinel<<<1, 1, 0, stream>>>(out);
        return;
    }

    hipMemsetAsync(degcnt, 0, (size_t)2 * NPAD * 4, stream);
    hipMemsetAsync(agg, 0, (size_t)N_NODES * 64 * 4, stream);
    k_node_enc<<<2500, 256, 0, stream>>>(x, nW1, nb1, nW2, nb2, kb3, h_a, h16_a, hb);
    k_cond_enc<<<1, 256, 0, stream>>>(conditions, scale, cW1, cb1, cW2, cb2, u, out + N_NODES);
    k_degcnt<<<(N_EDGES + 255) / 256, 256, 0, stream>>>(edge_index, deg, cnt);
    k_deg_inv<<<(N_NODES + 255) / 256, 256, 0, stream>>>(deg);
    k_csr_scan<<<1, 256, 0, stream>>>(cnt, srcPtr, cursor);
    k_csr_fill<<<(N_EDGES + 255) / 256, 256, 0, stream>>>(edge_index, cursor, srcIdx);
    k_mp2<<<dim3(64, 8), 256, 0, stream>>>(kW3, Mp2);
    k_edge12<<<EPAD / 16, 256, 0, stream>>>(edge_attr, edge_index, batch, u, kW1, kb1, kW2, kb2, k2);

    float* hc = h_a; float* hn = h_b;
    f16* hc16 = h16_a; f16* hn16 = h16_b;
    for (int l = 0; l < 3; ++l) {
        k_gmsg<<<dim3(8, NPAD / 16), 256, 0, stream>>>(k2, Mp2, hc16, hb, edge_index,
                                                       srcPtr, srcIdx, deg, agg);
        k_update<<<2500, 256, 0, stream>>>(agg, hc, root, conv_bias, kb3, hn, hn16, hb);
        float* tf = hc; hc = hn; hn = tf;
        f16* t16 = hc16; hc16 = hn16; hn16 = t16;
    }
    k_out<<<2500, 256, 0, stream>>>(hc, oW, ob, out);
}